// Round 6
// baseline (156.987 us; speedup 1.0000x reference)
//
#include <hip/hip_runtime.h>

typedef __bf16 bf16x8 __attribute__((ext_vector_type(8)));
typedef __bf16 bf16x4 __attribute__((ext_vector_type(4)));
typedef float f32x4 __attribute__((ext_vector_type(4)));
typedef unsigned short u16;
typedef unsigned int u32;
typedef u32 u32x4 __attribute__((ext_vector_type(4)));

// round-to-nearest-even f32 -> bf16
__device__ __forceinline__ u16 f2bf(float f) {
  u32 u = __builtin_bit_cast(u32, f);
  u += 0x7fffu + ((u >> 16) & 1u);
  return (u16)(u >> 16);
}

// packed f32x2 -> bf16x2 (RNE); low u16 = first arg (verified R2/R4)
__device__ __forceinline__ u32 cvt_pk_bf16(float lo, float hi) {
  u32 r;
  asm("v_cvt_pk_bf16_f32 %0, %1, %2" : "=v"(r) : "v"(lo), "v"(hi));
  return r;
}

// raw v_exp_f32: r = 2^x (scores pre-scaled to log2 domain)
__device__ __forceinline__ float ex2(float x) {
  float r;
  asm("v_exp_f32 %0, %1" : "=v"(r) : "v"(x));
  return r;
}

// async global->LDS, 16B per lane. LDS dest = wave-uniform base (HW adds lane*16).
__device__ __forceinline__ void gl_lds16(const u16* g, u16* l) {
  __builtin_amdgcn_global_load_lds(
      (const __attribute__((address_space(1))) u32*)g,
      (__attribute__((address_space(3))) u32*)l, 16, 0, 0);
}

// LDS transpose read. Per-lane address REQUIRED: p = base + lane*4 (elems).
// Lane l receives elems base[(l>>4)*64 + j*16 + (l&15)], j=0..3 (verified R4).
__device__ __forceinline__ bf16x4 tr16(const u16* p) {
  bf16x4 r;
  auto lp = (const __attribute__((address_space(3))) u16*)p;
  asm volatile("ds_read_b64_tr_b16 %0, %1" : "=&v"(r) : "v"(lp));
  return r;
}

// ---------------- cast x: f32 -> bf16, 8 elems/thread ----------------
__global__ __launch_bounds__(256) void k_cast(const float* __restrict__ in,
                                              u16* __restrict__ out, int n8) {
  int i = blockIdx.x * 256 + threadIdx.x;
  if (i >= n8) return;
  const float4* p = (const float4*)in + (size_t)i * 2;
  float4 a = p[0], b = p[1];
  u16 r[8] = {f2bf(a.x), f2bf(a.y), f2bf(a.z), f2bf(a.w),
              f2bf(b.x), f2bf(b.y), f2bf(b.z), f2bf(b.w)};
  ((uint4*)out)[i] = *(const uint4*)r;
}

// ---------- transpose+cast: W [K][N] f32 -> Wt [N][K] bf16 ----------
__global__ __launch_bounds__(256) void k_tcast(const float* __restrict__ in,
                                               u16* __restrict__ out, int K, int N) {
  __shared__ float tile[32][33];
  int n0 = blockIdx.x * 32, k0 = blockIdx.y * 32;
  int c = threadIdx.x & 31, r0 = (threadIdx.x >> 5) * 4;
#pragma unroll
  for (int rr = 0; rr < 4; ++rr) {
    int r = r0 + rr;
    tile[r][c] = in[(size_t)(k0 + r) * N + n0 + c];
  }
  __syncthreads();
#pragma unroll
  for (int rr = 0; rr < 4; ++rr) {
    int r = r0 + rr;
    out[(size_t)(n0 + r) * K + k0 + c] = f2bf(tile[c][r]);
  }
}

// ---------------- bf16 GEMM: C[M,N] = A[M,K] * Bt[N,K]^T ----------------
// 128x128 tile, 4 waves (2x2), BK=32. LDS chunk-swizzle: pchunk = chunk ^ ((row>>1)&3).
// EPI 0: Q scaled by 0.125*log2(e) (attention works in exp2 domain).
template <int EPI>
__global__ __launch_bounds__(256) void k_gemm(const u16* __restrict__ A,
                                              const u16* __restrict__ Bt,
                                              u16* __restrict__ Qp, u16* __restrict__ Kp,
                                              u16* __restrict__ Vp, float* __restrict__ Cf,
                                              int K) {
  __shared__ u16 As[128 * 32];
  __shared__ u16 Bs[128 * 32];
  const int tid = threadIdx.x;
  const int lane = tid & 63, wave = tid >> 6;
  const int l15 = lane & 15, l4 = lane >> 4;
  const int wr = wave >> 1, wc = wave & 1;
  const int tm = blockIdx.y, tn = blockIdx.x;

  int srow[2], scol[2];
#pragma unroll
  for (int i = 0; i < 2; ++i) {
    int row = (wave * 2 + i) * 16 + (lane >> 2);
    srow[i] = row;
    scol[i] = ((lane & 3) ^ ((row >> 1) & 3)) * 8;
  }

  const f32x4 fz = {0.f, 0.f, 0.f, 0.f};
  f32x4 acc[4][4];
#pragma unroll
  for (int a = 0; a < 4; ++a)
#pragma unroll
    for (int b = 0; b < 4; ++b) acc[a][b] = fz;

  const int nk = K >> 5;
  for (int kt = 0; kt < nk; ++kt) {
#pragma unroll
    for (int i = 0; i < 2; ++i) {
      gl_lds16(A + (size_t)(tm * 128 + srow[i]) * K + kt * 32 + scol[i],
               &As[(wave * 2 + i) * 512]);
      gl_lds16(Bt + (size_t)(tn * 128 + srow[i]) * K + kt * 32 + scol[i],
               &Bs[(wave * 2 + i) * 512]);
    }
    __syncthreads();
    bf16x8 af[4], bfr[4];
#pragma unroll
    for (int mi = 0; mi < 4; ++mi) {
      int row = wr * 64 + mi * 16 + l15;
      int pch = l4 ^ ((row >> 1) & 3);
      af[mi] = *(const bf16x8*)&As[row * 32 + pch * 8];
    }
#pragma unroll
    for (int ni = 0; ni < 4; ++ni) {
      int row = wc * 64 + ni * 16 + l15;
      int pch = l4 ^ ((row >> 1) & 3);
      bfr[ni] = *(const bf16x8*)&Bs[row * 32 + pch * 8];
    }
#pragma unroll
    for (int mi = 0; mi < 4; ++mi)
#pragma unroll
      for (int ni = 0; ni < 4; ++ni)
        acc[mi][ni] = __builtin_amdgcn_mfma_f32_16x16x32_bf16(af[mi], bfr[ni],
                                                              acc[mi][ni], 0, 0, 0);
    __syncthreads();
  }

  const int rbase = tm * 128 + wr * 64 + l4 * 4;
  const int cbase = tn * 128 + wc * 64 + l15;
  if (EPI == 0) {
#pragma unroll
    for (int ni = 0; ni < 4; ++ni) {
      int col = cbase + ni * 16;
      int which = col >> 10;
      int d = col & 1023;
      int h = d >> 6, hd = d & 63;
      u16* dst = which == 0 ? Qp : (which == 1 ? Kp : Vp);
      float scl = which == 0 ? 0.180336880f : 1.0f;  // 0.125 * log2(e)
#pragma unroll
      for (int mi = 0; mi < 4; ++mi) {
#pragma unroll
        for (int r = 0; r < 4; ++r) {
          int rowg = rbase + mi * 16 + r;
          int b = rowg >> 11, t = rowg & 2047;
          dst[(size_t)(((b * 16 + h) * 2048 + t) * 64 + hd)] = f2bf(acc[mi][ni][r] * scl);
        }
      }
    }
  } else {
#pragma unroll
    for (int mi = 0; mi < 4; ++mi)
#pragma unroll
      for (int r = 0; r < 4; ++r) {
        int rowg = rbase + mi * 16 + r;
#pragma unroll
        for (int ni = 0; ni < 4; ++ni)
          Cf[(size_t)rowg * 1024 + cbase + ni * 16] = acc[mi][ni][r];
      }
  }
}

// ---------------- causal flash attention (v5: barrier-free) ----------------
// grid (pair=16, bh=32); block does q-tiles qtA=31-p, qtB=p concurrently (33
// tile-units per block, exactly balanced). NO __syncthreads anywhere:
//  - K fragments loaded DIRECT from global (L2-resident, coalesced 16B/lane),
//    shared between tiles A and B.
//  - V staged WAVE-PRIVATE (each wave DMAs the full 8KB tile into its own
//    double-buffered LDS region via global_load_lds); own-wave vmcnt(0) is the
//    only wait -- placed where the queue is already empty except V(t).
//  - tr16 V-fragments shared between A and B.
__global__ __launch_bounds__(256, 2) void k_attn(const u16* __restrict__ Q,
                                                 const u16* __restrict__ K,
                                                 const u16* __restrict__ V,
                                                 u16* __restrict__ Y) {
  // per-wave, double-buffered, subtiled V: ((hd>>4)*16+(k>>2))*64+(k&3)*16+(hd&15)
  __shared__ u16 Vtr[4][2][64 * 64];  // 64 KB
  const int tid = threadIdx.x, lane = tid & 63, wave = tid >> 6;
  const int l15 = lane & 15, l4 = lane >> 4;
  const int bh = blockIdx.y;
  const int pp = (blockIdx.x + ((blockIdx.y >> 4) << 3)) & 15;
  const int qtA = 31 - pp, qtB = pp;
  const u16* Qb = Q + (size_t)bh * 2048 * 64;
  const u16* Kb = K + (size_t)bh * 2048 * 64;
  const u16* Vb = V + (size_t)bh * 2048 * 64;
  const int b = bh >> 4, h = bh & 15;
  const f32x4 fz = {0.f, 0.f, 0.f, 0.f};

  // V staging: linear LDS offset o -> (k, hd) of the subtiled layout (R4-verified)
  auto stageV = [&](int buf, int kt) {
#pragma unroll
    for (int i = 0; i < 8; ++i) {
      int o = i * 512 + lane * 8;
      int vk = ((o >> 6) & 15) * 4 + ((o >> 4) & 3);
      int vhd = ((o >> 10) << 4) + (o & 8);
      gl_lds16(Vb + (size_t)(kt * 64 + vk) * 64 + vhd, &Vtr[wave][buf][i * 512]);
    }
  };

  // softmax + pack P to bf16 frags (defer-max T13; exp2 domain)
  auto smxpack = [&](const f32x4* accS, float& m, float& lsum, f32x4* accO,
                     bool diag, bf16x8* pf) {
    float sv[4][4];
    if (diag) {
      int qg = wave * 16 + l15;
#pragma unroll
      for (int nb = 0; nb < 4; ++nb)
#pragma unroll
        for (int r = 0; r < 4; ++r) {
          int kg = nb * 16 + l4 * 4 + r;
          sv[nb][r] = kg > qg ? -1e30f : accS[nb][r];
        }
    } else {
#pragma unroll
      for (int nb = 0; nb < 4; ++nb)
#pragma unroll
        for (int r = 0; r < 4; ++r) sv[nb][r] = accS[nb][r];
    }
    float mx = sv[0][0];
#pragma unroll
    for (int nb = 0; nb < 4; ++nb)
#pragma unroll
      for (int r = 0; r < 4; ++r) mx = fmaxf(mx, sv[nb][r]);
    if (!__all(mx <= m + 8.0f)) {
      float mr = fmaxf(mx, __shfl_xor(mx, 16));
      mr = fmaxf(mr, __shfl_xor(mr, 32));
      float mnew = fmaxf(m, mr);
      float alpha = ex2(m - mnew);
      m = mnew;
      lsum *= alpha;
#pragma unroll
      for (int hb = 0; hb < 4; ++hb)
#pragma unroll
        for (int r = 0; r < 4; ++r) accO[hb][r] *= alpha;
    }
    float p[4][4];
    float rsum = 0.f;
#pragma unroll
    for (int nb = 0; nb < 4; ++nb)
#pragma unroll
      for (int r = 0; r < 4; ++r) {
        p[nb][r] = ex2(sv[nb][r] - m);
        rsum += p[nb][r];
      }
    lsum += rsum;  // group-partial; merged at epilogue
#pragma unroll
    for (int s = 0; s < 2; ++s) {
      u32x4 w;
      w.x = cvt_pk_bf16(p[2 * s][0], p[2 * s][1]);
      w.y = cvt_pk_bf16(p[2 * s][2], p[2 * s][3]);
      w.z = cvt_pk_bf16(p[2 * s + 1][0], p[2 * s + 1][1]);
      w.w = cvt_pk_bf16(p[2 * s + 1][2], p[2 * s + 1][3]);
      pf[s] = __builtin_bit_cast(bf16x8, w);
    }
  };

  // load Q fragments for both tiles
  bf16x8 qfA[2], qfB[2];
  {
    int qrA = qtA * 64 + wave * 16 + l15;
    int qrB = qtB * 64 + wave * 16 + l15;
    qfA[0] = *(const bf16x8*)&Qb[(size_t)qrA * 64 + l4 * 8];
    qfA[1] = *(const bf16x8*)&Qb[(size_t)qrA * 64 + 32 + l4 * 8];
    qfB[0] = *(const bf16x8*)&Qb[(size_t)qrB * 64 + l4 * 8];
    qfB[1] = *(const bf16x8*)&Qb[(size_t)qrB * 64 + 32 + l4 * 8];
  }
  f32x4 oA[4] = {fz, fz, fz, fz}, oB[4] = {fz, fz, fz, fz};
  float mA = -1e30f, lsA = 0.f, mB = -1e30f, lsB = 0.f;

  stageV(0, 0);  // prologue; waited by iter 0's vmcnt(0)

  int cur = 0;
#pragma unroll 1
  for (int kt = 0; kt <= qtA; ++kt) {
    const bool actB = kt <= qtB;

    // K fragments direct from global (shared by A and B)
    bf16x8 kf[2][4];
#pragma unroll
    for (int s = 0; s < 2; ++s)
#pragma unroll
      for (int nb = 0; nb < 4; ++nb)
        kf[s][nb] = *(const bf16x8*)&Kb[(size_t)(kt * 64 + nb * 16 + l15) * 64 +
                                        s * 32 + l4 * 8];

    // QK^T (swapped): accS[nb] = S[q=l15][k=nb*16+l4*4+r]
    f32x4 sA[4] = {fz, fz, fz, fz};
    f32x4 sB[4] = {fz, fz, fz, fz};
    __builtin_amdgcn_s_setprio(1);
#pragma unroll
    for (int s = 0; s < 2; ++s)
#pragma unroll
      for (int nb = 0; nb < 4; ++nb) {
        sA[nb] = __builtin_amdgcn_mfma_f32_16x16x32_bf16(kf[s][nb], qfA[s], sA[nb], 0, 0, 0);
        if (actB)
          sB[nb] = __builtin_amdgcn_mfma_f32_16x16x32_bf16(kf[s][nb], qfB[s], sB[nb], 0, 0, 0);
      }
    __builtin_amdgcn_s_setprio(0);

    bf16x8 pfA[2], pfB[2];
    smxpack(sA, mA, lsA, oA, kt == qtA, pfA);
    if (actB) smxpack(sB, mB, lsB, oB, kt == qtB, pfB);

    // wait own-wave V(kt) DMA (only it + consumed kf are outstanding here)
    asm volatile("s_waitcnt vmcnt(0)" ::: "memory");

    // tr16 V fragments (shared by A and B)
    bf16x8 vf[2][4];
#pragma unroll
    for (int s = 0; s < 2; ++s)
#pragma unroll
      for (int hb = 0; hb < 4; ++hb) {
        bf16x4 ta = tr16(&Vtr[wave][cur][(hb * 16 + s * 8) * 64 + lane * 4]);
        bf16x4 tb = tr16(&Vtr[wave][cur][(hb * 16 + s * 8 + 4) * 64 + lane * 4]);
        vf[s][hb] = __builtin_shufflevector(ta, tb, 0, 1, 2, 3, 4, 5, 6, 7);
      }
    asm volatile("s_waitcnt lgkmcnt(0)" ::: "memory");
    __builtin_amdgcn_sched_barrier(0);

    // O^T += V^T P^T
    __builtin_amdgcn_s_setprio(1);
#pragma unroll
    for (int s = 0; s < 2; ++s)
#pragma unroll
      for (int hb = 0; hb < 4; ++hb) {
        oA[hb] = __builtin_amdgcn_mfma_f32_16x16x32_bf16(vf[s][hb], pfA[s], oA[hb], 0, 0, 0);
        if (actB)
          oB[hb] = __builtin_amdgcn_mfma_f32_16x16x32_bf16(vf[s][hb], pfB[s], oB[hb], 0, 0, 0);
      }
    __builtin_amdgcn_s_setprio(0);

    // prefetch V(kt+1) into the other buffer (in flight across iterations)
    if (kt < qtA) stageV(cur ^ 1, kt + 1);
    cur ^= 1;
  }

  // epilogue: merge group-partial lsum (2 shuffles), divide, store
  auto epi = [&](f32x4* accO, float lsum, int qt) {
    float t = lsum + __shfl_xor(lsum, 16);
    t += __shfl_xor(t, 32);
    float inv = 1.0f / t;
    int qg = qt * 64 + wave * 16 + l15;
    u16* yrow = Y + (size_t)(b * 2048 + qg) * 1024 + h * 64;
#pragma unroll
    for (int hb = 0; hb < 4; ++hb) {
      uint2 pk;
      pk.x = cvt_pk_bf16(accO[hb][0] * inv, accO[hb][1] * inv);
      pk.y = cvt_pk_bf16(accO[hb][2] * inv, accO[hb][3] * inv);
      *(uint2*)&yrow[hb * 16 + l4 * 4] = pk;
    }
  };
  epi(oA, lsA, qtA);
  epi(oB, lsB, qtB);
}

extern "C" void kernel_launch(void* const* d_in, const int* in_sizes, int n_in,
                              void* d_out, int out_size, void* d_ws, size_t ws_size,
                              hipStream_t stream) {
  const float* x = (const float*)d_in[0];       // [2,2048,1024]
  const float* Wqkv = (const float*)d_in[1];    // [1024,3072]
  const float* Wproj = (const float*)d_in[2];   // [1024,1024]
  float* out = (float*)d_out;                   // [2,2048,1024] f32

  char* ws = (char*)d_ws;
  u16* Xb  = (u16*)(ws + 0);                    // 8 MB  [4096][1024]
  u16* Wqt = (u16*)(ws + ((size_t)8 << 20));    // 6 MB  [3072][1024]
  u16* Wpt = (u16*)(ws + ((size_t)14 << 20));   // 2 MB  [1024][1024]
  u16* Qs  = (u16*)(ws + ((size_t)16 << 20));   // 8 MB  [2,16,2048,64]
  u16* Ks  = (u16*)(ws + ((size_t)24 << 20));   // 8 MB
  u16* Vs  = (u16*)(ws + ((size_t)32 << 20));   // 8 MB
  u16* Yb  = (u16*)(ws + ((size_t)40 << 20));   // 8 MB  [4096][1024]

  k_cast<<<2048, 256, 0, stream>>>(x, Xb, 4096 * 1024 / 8);
  k_tcast<<<dim3(96, 32), 256, 0, stream>>>(Wqkv, Wqt, 1024, 3072);
  k_tcast<<<dim3(32, 32), 256, 0, stream>>>(Wproj, Wpt, 1024, 1024);
  k_gemm<0><<<dim3(24, 32), 256, 0, stream>>>(Xb, Wqt, Qs, Ks, Vs, nullptr, 1024);
  k_attn<<<dim3(16, 32), 256, 0, stream>>>(Qs, Ks, Vs, Yb);
  k_gemm<1><<<dim3(8, 32), 256, 0, stream>>>(Yb, Wpt, nullptr, nullptr, nullptr, out, 1024);
}

// Round 7
// 125.536 us; speedup vs baseline: 1.2505x; 1.2505x over previous
//
#include <hip/hip_runtime.h>

typedef __bf16 bf16x8 __attribute__((ext_vector_type(8)));
typedef __bf16 bf16x4 __attribute__((ext_vector_type(4)));
typedef float f32x4 __attribute__((ext_vector_type(4)));
typedef unsigned short u16;
typedef unsigned int u32;
typedef u32 u32x4 __attribute__((ext_vector_type(4)));

// round-to-nearest-even f32 -> bf16
__device__ __forceinline__ u16 f2bf(float f) {
  u32 u = __builtin_bit_cast(u32, f);
  u += 0x7fffu + ((u >> 16) & 1u);
  return (u16)(u >> 16);
}

// packed f32x2 -> bf16x2 (RNE); low u16 = first arg (verified R2/R4)
__device__ __forceinline__ u32 cvt_pk_bf16(float lo, float hi) {
  u32 r;
  asm("v_cvt_pk_bf16_f32 %0, %1, %2" : "=v"(r) : "v"(lo), "v"(hi));
  return r;
}

// raw v_exp_f32: r = 2^x (scores pre-scaled to log2 domain)
__device__ __forceinline__ float ex2(float x) {
  float r;
  asm("v_exp_f32 %0, %1" : "=v"(r) : "v"(x));
  return r;
}

// async global->LDS, 16B per lane. LDS dest = wave-uniform base (HW adds lane*16).
__device__ __forceinline__ void gl_lds16(const u16* g, u16* l) {
  __builtin_amdgcn_global_load_lds(
      (const __attribute__((address_space(1))) u32*)g,
      (__attribute__((address_space(3))) u32*)l, 16, 0, 0);
}

// LDS transpose read. Per-lane address REQUIRED: p = base + lane*4 (elems).
// Lane l receives elems base[(l>>4)*64 + j*16 + (l&15)], j=0..3 (verified R4).
__device__ __forceinline__ bf16x4 tr16(const u16* p) {
  bf16x4 r;
  auto lp = (const __attribute__((address_space(3))) u16*)p;
  asm volatile("ds_read_b64_tr_b16 %0, %1" : "=&v"(r) : "v"(lp));
  return r;
}

// ---------------- cast x: f32 -> bf16, 8 elems/thread ----------------
__global__ __launch_bounds__(256) void k_cast(const float* __restrict__ in,
                                              u16* __restrict__ out, int n8) {
  int i = blockIdx.x * 256 + threadIdx.x;
  if (i >= n8) return;
  const float4* p = (const float4*)in + (size_t)i * 2;
  float4 a = p[0], b = p[1];
  u16 r[8] = {f2bf(a.x), f2bf(a.y), f2bf(a.z), f2bf(a.w),
              f2bf(b.x), f2bf(b.y), f2bf(b.z), f2bf(b.w)};
  ((uint4*)out)[i] = *(const uint4*)r;
}

// ---------- transpose+cast: W [K][N] f32 -> Wt [N][K] bf16 ----------
__global__ __launch_bounds__(256) void k_tcast(const float* __restrict__ in,
                                               u16* __restrict__ out, int K, int N) {
  __shared__ float tile[32][33];
  int n0 = blockIdx.x * 32, k0 = blockIdx.y * 32;
  int c = threadIdx.x & 31, r0 = (threadIdx.x >> 5) * 4;
#pragma unroll
  for (int rr = 0; rr < 4; ++rr) {
    int r = r0 + rr;
    tile[r][c] = in[(size_t)(k0 + r) * N + n0 + c];
  }
  __syncthreads();
#pragma unroll
  for (int rr = 0; rr < 4; ++rr) {
    int r = r0 + rr;
    out[(size_t)(n0 + r) * K + k0 + c] = f2bf(tile[c][r]);
  }
}

// ---------------- bf16 GEMM: C[M,N] = A[M,K] * Bt[N,K]^T ----------------
// 128x128 tile, 4 waves (2x2), BK=32. LDS chunk-swizzle: pchunk = chunk ^ ((row>>1)&3).
// EPI 0: Q scaled by 0.125*log2(e) (attention works in exp2 domain).
template <int EPI>
__global__ __launch_bounds__(256) void k_gemm(const u16* __restrict__ A,
                                              const u16* __restrict__ Bt,
                                              u16* __restrict__ Qp, u16* __restrict__ Kp,
                                              u16* __restrict__ Vp, float* __restrict__ Cf,
                                              int K) {
  __shared__ u16 As[128 * 32];
  __shared__ u16 Bs[128 * 32];
  const int tid = threadIdx.x;
  const int lane = tid & 63, wave = tid >> 6;
  const int l15 = lane & 15, l4 = lane >> 4;
  const int wr = wave >> 1, wc = wave & 1;
  const int tm = blockIdx.y, tn = blockIdx.x;

  int srow[2], scol[2];
#pragma unroll
  for (int i = 0; i < 2; ++i) {
    int row = (wave * 2 + i) * 16 + (lane >> 2);
    srow[i] = row;
    scol[i] = ((lane & 3) ^ ((row >> 1) & 3)) * 8;
  }

  const f32x4 fz = {0.f, 0.f, 0.f, 0.f};
  f32x4 acc[4][4];
#pragma unroll
  for (int a = 0; a < 4; ++a)
#pragma unroll
    for (int b = 0; b < 4; ++b) acc[a][b] = fz;

  const int nk = K >> 5;
  for (int kt = 0; kt < nk; ++kt) {
#pragma unroll
    for (int i = 0; i < 2; ++i) {
      gl_lds16(A + (size_t)(tm * 128 + srow[i]) * K + kt * 32 + scol[i],
               &As[(wave * 2 + i) * 512]);
      gl_lds16(Bt + (size_t)(tn * 128 + srow[i]) * K + kt * 32 + scol[i],
               &Bs[(wave * 2 + i) * 512]);
    }
    __syncthreads();
    bf16x8 af[4], bfr[4];
#pragma unroll
    for (int mi = 0; mi < 4; ++mi) {
      int row = wr * 64 + mi * 16 + l15;
      int pch = l4 ^ ((row >> 1) & 3);
      af[mi] = *(const bf16x8*)&As[row * 32 + pch * 8];
    }
#pragma unroll
    for (int ni = 0; ni < 4; ++ni) {
      int row = wc * 64 + ni * 16 + l15;
      int pch = l4 ^ ((row >> 1) & 3);
      bfr[ni] = *(const bf16x8*)&Bs[row * 32 + pch * 8];
    }
#pragma unroll
    for (int mi = 0; mi < 4; ++mi)
#pragma unroll
      for (int ni = 0; ni < 4; ++ni)
        acc[mi][ni] = __builtin_amdgcn_mfma_f32_16x16x32_bf16(af[mi], bfr[ni],
                                                              acc[mi][ni], 0, 0, 0);
    __syncthreads();
  }

  const int rbase = tm * 128 + wr * 64 + l4 * 4;
  const int cbase = tn * 128 + wc * 64 + l15;
  if (EPI == 0) {
#pragma unroll
    for (int ni = 0; ni < 4; ++ni) {
      int col = cbase + ni * 16;
      int which = col >> 10;
      int d = col & 1023;
      int h = d >> 6, hd = d & 63;
      u16* dst = which == 0 ? Qp : (which == 1 ? Kp : Vp);
      float scl = which == 0 ? 0.180336880f : 1.0f;  // 0.125 * log2(e)
#pragma unroll
      for (int mi = 0; mi < 4; ++mi) {
#pragma unroll
        for (int r = 0; r < 4; ++r) {
          int rowg = rbase + mi * 16 + r;
          int b = rowg >> 11, t = rowg & 2047;
          dst[(size_t)(((b * 16 + h) * 2048 + t) * 64 + hd)] = f2bf(acc[mi][ni][r] * scl);
        }
      }
    }
  } else {
#pragma unroll
    for (int mi = 0; mi < 4; ++mi)
#pragma unroll
      for (int r = 0; r < 4; ++r) {
        int rowg = rbase + mi * 16 + r;
#pragma unroll
        for (int ni = 0; ni < 4; ++ni)
          Cf[(size_t)rowg * 1024 + cbase + ni * 16] = acc[mi][ni][r];
      }
  }
}

// ---------------- causal flash attention (v6: R5 + counted-vmcnt pipeline) ----------------
// grid (pair=16, bh=32); block does q-tiles qtA=31-p, qtB=p concurrently.
// Shared cooperative K/V^T staging (R5-verified maps), TRIPLE-buffered.
// Raw s_barrier + s_waitcnt vmcnt(8): tile kt+1 and kt+2 DMAs stay in flight
// across barriers (T4); the queue is never drained in the loop.
// Invariant: exactly 12 stage-ops issued-unwaited at each iteration top
// (tail stages clamp to tile qtA into dead slots to keep the count exact).
__global__ __launch_bounds__(256) void k_attn(const u16* __restrict__ Q,
                                              const u16* __restrict__ K,
                                              const u16* __restrict__ V,
                                              u16* __restrict__ Y) {
  __shared__ u16 Kl[3][64 * 64];   // [kk][hd], chunk ^= kk&7
  __shared__ u16 Vtr[3][64 * 64];  // subtiled: ((hd>>4)*16+(k>>2))*64 + (k&3)*16 + (hd&15)
  const int tid = threadIdx.x, lane = tid & 63, wave = tid >> 6;
  const int l15 = lane & 15, l4 = lane >> 4;
  const int bh = blockIdx.y;
  const int pp = (blockIdx.x + ((blockIdx.y >> 4) << 3)) & 15;  // co-res blocks differ
  const int qtA = 31 - pp, qtB = pp;
  const u16* Qb = Q + (size_t)bh * 2048 * 64;
  const u16* Kb = K + (size_t)bh * 2048 * 64;
  const u16* Vb = V + (size_t)bh * 2048 * 64;
  const int b = bh >> 4, h = bh & 15;
  const f32x4 fz = {0.f, 0.f, 0.f, 0.f};

  // K staging (pre-swizzled global source, linear LDS dest)
  const int kk0 = wave * 16 + (lane >> 3);
  const int kk1 = kk0 + 8;
  const int lcol0 = ((lane & 7) ^ (kk0 & 7)) * 8;
  const int lcol1 = ((lane & 7) ^ (kk1 & 7)) * 8;
  // V staging: linear LDS offset o -> (k, hd) of the subtiled layout
  int vk[2], vhd[2];
#pragma unroll
  for (int i = 0; i < 2; ++i) {
    int o = (wave * 2 + i) * 512 + lane * 8;
    vk[i] = ((o >> 6) & 15) * 4 + ((o >> 4) & 3);
    vhd[i] = ((o >> 10) << 4) + (o & 8);
  }

  // 4 VMEM ops per wave per stage
  auto stage = [&](int buf, int kt) {
    gl_lds16(Kb + (size_t)(kt * 64 + kk0) * 64 + lcol0, &Kl[buf][(wave * 2 + 0) * 512]);
    gl_lds16(Kb + (size_t)(kt * 64 + kk1) * 64 + lcol1, &Kl[buf][(wave * 2 + 1) * 512]);
    gl_lds16(Vb + (size_t)(kt * 64 + vk[0]) * 64 + vhd[0], &Vtr[buf][(wave * 2 + 0) * 512]);
    gl_lds16(Vb + (size_t)(kt * 64 + vk[1]) * 64 + vhd[1], &Vtr[buf][(wave * 2 + 1) * 512]);
  };

  auto qk = [&](const bf16x8* qf, f32x4* accS, int cur) {
    __builtin_amdgcn_s_setprio(1);
#pragma unroll
    for (int s = 0; s < 2; ++s)
#pragma unroll
      for (int nb = 0; nb < 4; ++nb) {
        int kk = nb * 16 + l15;
        int ch = (s * 4 + l4) ^ (kk & 7);
        bf16x8 kf = *(const bf16x8*)&Kl[cur][kk * 64 + ch * 8];
        accS[nb] = __builtin_amdgcn_mfma_f32_16x16x32_bf16(kf, qf[s], accS[nb], 0, 0, 0);
      }
    __builtin_amdgcn_s_setprio(0);
  };

  auto smx = [&](const f32x4* accS, float (*p)[4], float& m, float& lsum,
                 f32x4* accO, bool diag) {
    float sv[4][4];
    if (diag) {
      int qg = wave * 16 + l15;
#pragma unroll
      for (int nb = 0; nb < 4; ++nb)
#pragma unroll
        for (int r = 0; r < 4; ++r) {
          int kg = nb * 16 + l4 * 4 + r;
          sv[nb][r] = kg > qg ? -1e30f : accS[nb][r];
        }
    } else {
#pragma unroll
      for (int nb = 0; nb < 4; ++nb)
#pragma unroll
        for (int r = 0; r < 4; ++r) sv[nb][r] = accS[nb][r];
    }
    float mx = sv[0][0];
#pragma unroll
    for (int nb = 0; nb < 4; ++nb)
#pragma unroll
      for (int r = 0; r < 4; ++r) mx = fmaxf(mx, sv[nb][r]);
    // defer-max: common path has NO cross-lane ops and NO rescale
    if (!__all(mx <= m + 8.0f)) {
      float mr = fmaxf(mx, __shfl_xor(mx, 16));
      mr = fmaxf(mr, __shfl_xor(mr, 32));
      float mnew = fmaxf(m, mr);
      float alpha = ex2(m - mnew);
      m = mnew;
      lsum *= alpha;
#pragma unroll
      for (int hb = 0; hb < 4; ++hb)
#pragma unroll
        for (int r = 0; r < 4; ++r) accO[hb][r] *= alpha;
    }
    float rsum = 0.f;
#pragma unroll
    for (int nb = 0; nb < 4; ++nb)
#pragma unroll
      for (int r = 0; r < 4; ++r) {
        p[nb][r] = ex2(sv[nb][r] - m);
        rsum += p[nb][r];
      }
    lsum += rsum;  // group-partial; merged at epilogue
  };

  auto pv = [&](const float (*p)[4], f32x4* accO, int cur) {
#pragma unroll
    for (int s = 0; s < 2; ++s) {
      u32x4 w;
      w.x = cvt_pk_bf16(p[2 * s][0], p[2 * s][1]);
      w.y = cvt_pk_bf16(p[2 * s][2], p[2 * s][3]);
      w.z = cvt_pk_bf16(p[2 * s + 1][0], p[2 * s + 1][1]);
      w.w = cvt_pk_bf16(p[2 * s + 1][2], p[2 * s + 1][3]);
      bf16x8 pf = __builtin_bit_cast(bf16x8, w);
      bf16x4 ta[4], tb[4];
#pragma unroll
      for (int hb = 0; hb < 4; ++hb) {
        ta[hb] = tr16(&Vtr[cur][(hb * 16 + s * 8) * 64 + lane * 4]);
        tb[hb] = tr16(&Vtr[cur][(hb * 16 + s * 8 + 4) * 64 + lane * 4]);
      }
      asm volatile("s_waitcnt lgkmcnt(0)" ::: "memory");
      __builtin_amdgcn_sched_barrier(0);
      __builtin_amdgcn_s_setprio(1);
#pragma unroll
      for (int hb = 0; hb < 4; ++hb) {
        bf16x8 vf = __builtin_shufflevector(ta[hb], tb[hb], 0, 1, 2, 3, 4, 5, 6, 7);
        accO[hb] = __builtin_amdgcn_mfma_f32_16x16x32_bf16(vf, pf, accO[hb], 0, 0, 0);
      }
      __builtin_amdgcn_s_setprio(0);
    }
  };

  // load Q fragments for both tiles (retired by the first vmcnt(8))
  bf16x8 qfA[2], qfB[2];
  {
    int qrA = qtA * 64 + wave * 16 + l15;
    int qrB = qtB * 64 + wave * 16 + l15;
    qfA[0] = *(const bf16x8*)&Qb[(size_t)qrA * 64 + l4 * 8];
    qfA[1] = *(const bf16x8*)&Qb[(size_t)qrA * 64 + 32 + l4 * 8];
    qfB[0] = *(const bf16x8*)&Qb[(size_t)qrB * 64 + l4 * 8];
    qfB[1] = *(const bf16x8*)&Qb[(size_t)qrB * 64 + 32 + l4 * 8];
  }
  f32x4 oA[4] = {fz, fz, fz, fz}, oB[4] = {fz, fz, fz, fz};
  float mA = -1e30f, lsA = 0.f, mB = -1e30f, lsB = 0.f;

  // prologue: 3 tiles in flight (qtA >= 16 always)
  stage(0, 0);
  stage(1, 1);
  stage(2, 2);

  int cur = 0;
#pragma unroll 1
  for (int kt = 0; kt <= qtA; ++kt) {
    // retire tile kt's DMAs (own-wave), keep kt+1/kt+2 in flight
    asm volatile("s_waitcnt vmcnt(8)" ::: "memory");
    __builtin_amdgcn_s_barrier();           // all waves' kt data landed
    __builtin_amdgcn_sched_barrier(0);      // keep reads below the barrier

    const bool actB = kt <= qtB;
    f32x4 sA[4] = {fz, fz, fz, fz};
    f32x4 sB[4] = {fz, fz, fz, fz};
    qk(qfA, sA, cur);
    if (actB) qk(qfB, sB, cur);
    float pA[4][4], pB[4][4];
    smx(sA, pA, mA, lsA, oA, kt == qtA);
    if (actB) smx(sB, pB, mB, lsB, oB, kt == qtB);
    pv(pA, oA, cur);
    if (actB) pv(pB, oB, cur);

    __builtin_amdgcn_s_barrier();           // all waves done reading buf[cur]
    __builtin_amdgcn_sched_barrier(0);      // keep stage below the barrier
    // refill the just-read buffer; clamp keeps 4 ops issued EVERY iteration
    // (dead-slot rewrites of tile qtA are never read -- harmless)
    int nt = kt + 3 > qtA ? qtA : kt + 3;
    stage(cur, nt);
    cur = cur == 2 ? 0 : cur + 1;
  }

  // epilogue: merge group-partial lsum (2 shuffles), divide, store
  auto epi = [&](f32x4* accO, float lsum, int qt) {
    float t = lsum + __shfl_xor(lsum, 16);
    t += __shfl_xor(t, 32);
    float inv = 1.0f / t;
    int qg = qt * 64 + wave * 16 + l15;
    u16* yrow = Y + (size_t)(b * 2048 + qg) * 1024 + h * 64;
#pragma unroll
    for (int hb = 0; hb < 4; ++hb) {
      uint2 pk;
      pk.x = cvt_pk_bf16(accO[hb][0] * inv, accO[hb][1] * inv);
      pk.y = cvt_pk_bf16(accO[hb][2] * inv, accO[hb][3] * inv);
      *(uint2*)&yrow[hb * 16 + l4 * 4] = pk;
    }
  };
  epi(oA, lsA, qtA);
  epi(oB, lsB, qtB);
}

extern "C" void kernel_launch(void* const* d_in, const int* in_sizes, int n_in,
                              void* d_out, int out_size, void* d_ws, size_t ws_size,
                              hipStream_t stream) {
  const float* x = (const float*)d_in[0];       // [2,2048,1024]
  const float* Wqkv = (const float*)d_in[1];    // [1024,3072]
  const float* Wproj = (const float*)d_in[2];   // [1024,1024]
  float* out = (float*)d_out;                   // [2,2048,1024] f32

  char* ws = (char*)d_ws;
  u16* Xb  = (u16*)(ws + 0);                    // 8 MB  [4096][1024]
  u16* Wqt = (u16*)(ws + ((size_t)8 << 20));    // 6 MB  [3072][1024]
  u16* Wpt = (u16*)(ws + ((size_t)14 << 20));   // 2 MB  [1024][1024]
  u16* Qs  = (u16*)(ws + ((size_t)16 << 20));   // 8 MB  [2,16,2048,64]
  u16* Ks  = (u16*)(ws + ((size_t)24 << 20));   // 8 MB
  u16* Vs  = (u16*)(ws + ((size_t)32 << 20));   // 8 MB
  u16* Yb  = (u16*)(ws + ((size_t)40 << 20));   // 8 MB  [4096][1024]

  k_cast<<<2048, 256, 0, stream>>>(x, Xb, 4096 * 1024 / 8);
  k_tcast<<<dim3(96, 32), 256, 0, stream>>>(Wqkv, Wqt, 1024, 3072);
  k_tcast<<<dim3(32, 32), 256, 0, stream>>>(Wproj, Wpt, 1024, 1024);
  k_gemm<0><<<dim3(24, 32), 256, 0, stream>>>(Xb, Wqt, Qs, Ks, Vs, nullptr, 1024);
  k_attn<<<dim3(16, 32), 256, 0, stream>>>(Qs, Ks, Vs, Yb);
  k_gemm<1><<<dim3(8, 32), 256, 0, stream>>>(Yb, Wpt, nullptr, nullptr, nullptr, out, 1024);
}

// Round 8
// 120.906 us; speedup vs baseline: 1.2984x; 1.0383x over previous
//
#include <hip/hip_runtime.h>

typedef __bf16 bf16x8 __attribute__((ext_vector_type(8)));
typedef __bf16 bf16x4 __attribute__((ext_vector_type(4)));
typedef float f32x4 __attribute__((ext_vector_type(4)));
typedef unsigned short u16;
typedef unsigned int u32;
typedef u32 u32x4 __attribute__((ext_vector_type(4)));

// round-to-nearest-even f32 -> bf16
__device__ __forceinline__ u16 f2bf(float f) {
  u32 u = __builtin_bit_cast(u32, f);
  u += 0x7fffu + ((u >> 16) & 1u);
  return (u16)(u >> 16);
}

// packed f32x2 -> bf16x2 (RNE); low u16 = first arg (verified R2/R4)
__device__ __forceinline__ u32 cvt_pk_bf16(float lo, float hi) {
  u32 r;
  asm("v_cvt_pk_bf16_f32 %0, %1, %2" : "=v"(r) : "v"(lo), "v"(hi));
  return r;
}

// raw v_exp_f32: r = 2^x (scores pre-scaled to log2 domain)
__device__ __forceinline__ float ex2(float x) {
  float r;
  asm("v_exp_f32 %0, %1" : "=v"(r) : "v"(x));
  return r;
}

// async global->LDS, 16B per lane. LDS dest = wave-uniform base (HW adds lane*16).
__device__ __forceinline__ void gl_lds16(const u16* g, u16* l) {
  __builtin_amdgcn_global_load_lds(
      (const __attribute__((address_space(1))) u32*)g,
      (__attribute__((address_space(3))) u32*)l, 16, 0, 0);
}

// LDS transpose read. Per-lane address REQUIRED: p = base + lane*4 (elems).
// Lane l receives elems base[(l>>4)*64 + j*16 + (l&15)], j=0..3 (verified R4).
__device__ __forceinline__ bf16x4 tr16(const u16* p) {
  bf16x4 r;
  auto lp = (const __attribute__((address_space(3))) u16*)p;
  asm volatile("ds_read_b64_tr_b16 %0, %1" : "=&v"(r) : "v"(lp));
  return r;
}

// ---------------- cast x: f32 -> bf16, 8 elems/thread ----------------
__global__ __launch_bounds__(256) void k_cast(const float* __restrict__ in,
                                              u16* __restrict__ out, int n8) {
  int i = blockIdx.x * 256 + threadIdx.x;
  if (i >= n8) return;
  const float4* p = (const float4*)in + (size_t)i * 2;
  float4 a = p[0], b = p[1];
  u16 r[8] = {f2bf(a.x), f2bf(a.y), f2bf(a.z), f2bf(a.w),
              f2bf(b.x), f2bf(b.y), f2bf(b.z), f2bf(b.w)};
  ((uint4*)out)[i] = *(const uint4*)r;
}

// ---------- transpose+cast: W [K][N] f32 -> Wt [N][K] bf16 ----------
__global__ __launch_bounds__(256) void k_tcast(const float* __restrict__ in,
                                               u16* __restrict__ out, int K, int N) {
  __shared__ float tile[32][33];
  int n0 = blockIdx.x * 32, k0 = blockIdx.y * 32;
  int c = threadIdx.x & 31, r0 = (threadIdx.x >> 5) * 4;
#pragma unroll
  for (int rr = 0; rr < 4; ++rr) {
    int r = r0 + rr;
    tile[r][c] = in[(size_t)(k0 + r) * N + n0 + c];
  }
  __syncthreads();
#pragma unroll
  for (int rr = 0; rr < 4; ++rr) {
    int r = r0 + rr;
    out[(size_t)(n0 + r) * K + k0 + c] = f2bf(tile[c][r]);
  }
}

// ---------------- bf16 GEMM: C[M,N] = A[M,K] * Bt[N,K]^T ----------------
// 128x128 tile, 4 waves (2x2), BK=32. LDS chunk-swizzle: pchunk = chunk ^ ((row>>1)&3).
// EPI 0: Q scaled by 0.125*log2(e) (attention works in exp2 domain).
template <int EPI>
__global__ __launch_bounds__(256) void k_gemm(const u16* __restrict__ A,
                                              const u16* __restrict__ Bt,
                                              u16* __restrict__ Qp, u16* __restrict__ Kp,
                                              u16* __restrict__ Vp, float* __restrict__ Cf,
                                              int K) {
  __shared__ u16 As[128 * 32];
  __shared__ u16 Bs[128 * 32];
  const int tid = threadIdx.x;
  const int lane = tid & 63, wave = tid >> 6;
  const int l15 = lane & 15, l4 = lane >> 4;
  const int wr = wave >> 1, wc = wave & 1;
  const int tm = blockIdx.y, tn = blockIdx.x;

  int srow[2], scol[2];
#pragma unroll
  for (int i = 0; i < 2; ++i) {
    int row = (wave * 2 + i) * 16 + (lane >> 2);
    srow[i] = row;
    scol[i] = ((lane & 3) ^ ((row >> 1) & 3)) * 8;
  }

  const f32x4 fz = {0.f, 0.f, 0.f, 0.f};
  f32x4 acc[4][4];
#pragma unroll
  for (int a = 0; a < 4; ++a)
#pragma unroll
    for (int b = 0; b < 4; ++b) acc[a][b] = fz;

  const int nk = K >> 5;
  for (int kt = 0; kt < nk; ++kt) {
#pragma unroll
    for (int i = 0; i < 2; ++i) {
      gl_lds16(A + (size_t)(tm * 128 + srow[i]) * K + kt * 32 + scol[i],
               &As[(wave * 2 + i) * 512]);
      gl_lds16(Bt + (size_t)(tn * 128 + srow[i]) * K + kt * 32 + scol[i],
               &Bs[(wave * 2 + i) * 512]);
    }
    __syncthreads();
    bf16x8 af[4], bfr[4];
#pragma unroll
    for (int mi = 0; mi < 4; ++mi) {
      int row = wr * 64 + mi * 16 + l15;
      int pch = l4 ^ ((row >> 1) & 3);
      af[mi] = *(const bf16x8*)&As[row * 32 + pch * 8];
    }
#pragma unroll
    for (int ni = 0; ni < 4; ++ni) {
      int row = wc * 64 + ni * 16 + l15;
      int pch = l4 ^ ((row >> 1) & 3);
      bfr[ni] = *(const bf16x8*)&Bs[row * 32 + pch * 8];
    }
#pragma unroll
    for (int mi = 0; mi < 4; ++mi)
#pragma unroll
      for (int ni = 0; ni < 4; ++ni)
        acc[mi][ni] = __builtin_amdgcn_mfma_f32_16x16x32_bf16(af[mi], bfr[ni],
                                                              acc[mi][ni], 0, 0, 0);
    __syncthreads();
  }

  const int rbase = tm * 128 + wr * 64 + l4 * 4;
  const int cbase = tn * 128 + wc * 64 + l15;
  if (EPI == 0) {
#pragma unroll
    for (int ni = 0; ni < 4; ++ni) {
      int col = cbase + ni * 16;
      int which = col >> 10;
      int d = col & 1023;
      int h = d >> 6, hd = d & 63;
      u16* dst = which == 0 ? Qp : (which == 1 ? Kp : Vp);
      float scl = which == 0 ? 0.180336880f : 1.0f;  // 0.125 * log2(e)
#pragma unroll
      for (int mi = 0; mi < 4; ++mi) {
#pragma unroll
        for (int r = 0; r < 4; ++r) {
          int rowg = rbase + mi * 16 + r;
          int b = rowg >> 11, t = rowg & 2047;
          dst[(size_t)(((b * 16 + h) * 2048 + t) * 64 + hd)] = f2bf(acc[mi][ni][r] * scl);
        }
      }
    }
  } else {
#pragma unroll
    for (int mi = 0; mi < 4; ++mi)
#pragma unroll
      for (int r = 0; r < 4; ++r) {
        int rowg = rbase + mi * 16 + r;
#pragma unroll
        for (int ni = 0; ni < 4; ++ni)
          Cf[(size_t)rowg * 1024 + cbase + ni * 16] = acc[mi][ni][r];
      }
  }
}

// ---------------- causal flash attention (v7) ----------------
// grid (pair=16, bh=32); q-tiles qtA=31-p (always >qtB) and qtB=p.
// Phase 1 (kt<=qtB): A and B fused in ONE basic block -- tree max/sum,
// interleaved A/B chains, single rescale branch, SHARED vf tr-reads.
// Phase 2 (kt in (qtB, qtA]): A only. Triple-buffered counted-vmcnt staging.
__global__ __launch_bounds__(256) void k_attn(const u16* __restrict__ Q,
                                              const u16* __restrict__ K,
                                              const u16* __restrict__ V,
                                              u16* __restrict__ Y) {
  __shared__ u16 Kl[3][64 * 64];   // [kk][hd], chunk ^= kk&7
  __shared__ u16 Vtr[3][64 * 64];  // subtiled: ((hd>>4)*16+(k>>2))*64+(k&3)*16+(hd&15)
  const int tid = threadIdx.x, lane = tid & 63, wave = tid >> 6;
  const int l15 = lane & 15, l4 = lane >> 4;
  const int bh = blockIdx.y;
  const int pp = (blockIdx.x + ((blockIdx.y >> 4) << 3)) & 15;
  const int qtA = 31 - pp, qtB = pp;  // qtB < qtA always
  const u16* Qb = Q + (size_t)bh * 2048 * 64;
  const u16* Kb = K + (size_t)bh * 2048 * 64;
  const u16* Vb = V + (size_t)bh * 2048 * 64;
  const int b = bh >> 4, h = bh & 15;
  const f32x4 fz = {0.f, 0.f, 0.f, 0.f};

  const int kk0 = wave * 16 + (lane >> 3);
  const int kk1 = kk0 + 8;
  const int lcol0 = ((lane & 7) ^ (kk0 & 7)) * 8;
  const int lcol1 = ((lane & 7) ^ (kk1 & 7)) * 8;
  int vk[2], vhd[2];
#pragma unroll
  for (int i = 0; i < 2; ++i) {
    int o = (wave * 2 + i) * 512 + lane * 8;
    vk[i] = ((o >> 6) & 15) * 4 + ((o >> 4) & 3);
    vhd[i] = ((o >> 10) << 4) + (o & 8);
  }

  // 4 VMEM ops per wave per stage
  auto stage = [&](int buf, int kt) {
    gl_lds16(Kb + (size_t)(kt * 64 + kk0) * 64 + lcol0, &Kl[buf][(wave * 2 + 0) * 512]);
    gl_lds16(Kb + (size_t)(kt * 64 + kk1) * 64 + lcol1, &Kl[buf][(wave * 2 + 1) * 512]);
    gl_lds16(Vb + (size_t)(kt * 64 + vk[0]) * 64 + vhd[0], &Vtr[buf][(wave * 2 + 0) * 512]);
    gl_lds16(Vb + (size_t)(kt * 64 + vk[1]) * 64 + vhd[1], &Vtr[buf][(wave * 2 + 1) * 512]);
  };

  bf16x8 qfA[2], qfB[2];
  {
    int qrA = qtA * 64 + wave * 16 + l15;
    int qrB = qtB * 64 + wave * 16 + l15;
    qfA[0] = *(const bf16x8*)&Qb[(size_t)qrA * 64 + l4 * 8];
    qfA[1] = *(const bf16x8*)&Qb[(size_t)qrA * 64 + 32 + l4 * 8];
    qfB[0] = *(const bf16x8*)&Qb[(size_t)qrB * 64 + l4 * 8];
    qfB[1] = *(const bf16x8*)&Qb[(size_t)qrB * 64 + 32 + l4 * 8];
  }
  f32x4 oA[4] = {fz, fz, fz, fz}, oB[4] = {fz, fz, fz, fz};
  float mA = -1e30f, lsA = 0.f, mB = -1e30f, lsB = 0.f;

  stage(0, 0);
  stage(1, 1);
  stage(2, 2);

  int cur = 0, kt = 0;

  // ======== phase 1: both tiles active (kt = 0..qtB) ========
#pragma unroll 1
  for (; kt <= qtB; ++kt) {
    asm volatile("s_waitcnt vmcnt(8)" ::: "memory");
    __builtin_amdgcn_s_barrier();
    __builtin_amdgcn_sched_barrier(0);

    f32x4 sA[4] = {fz, fz, fz, fz}, sB[4] = {fz, fz, fz, fz};
    __builtin_amdgcn_s_setprio(1);
#pragma unroll
    for (int s = 0; s < 2; ++s)
#pragma unroll
      for (int nb = 0; nb < 4; ++nb) {
        int kk = nb * 16 + l15;
        int ch = (s * 4 + l4) ^ (kk & 7);
        bf16x8 kf = *(const bf16x8*)&Kl[cur][kk * 64 + ch * 8];
        sA[nb] = __builtin_amdgcn_mfma_f32_16x16x32_bf16(kf, qfA[s], sA[nb], 0, 0, 0);
        sB[nb] = __builtin_amdgcn_mfma_f32_16x16x32_bf16(kf, qfB[s], sB[nb], 0, 0, 0);
      }
    __builtin_amdgcn_s_setprio(0);

    // flatten; mask B on its diagonal tile
    float vA[16], vB[16];
#pragma unroll
    for (int nb = 0; nb < 4; ++nb)
#pragma unroll
      for (int r = 0; r < 4; ++r) {
        vA[nb * 4 + r] = sA[nb][r];
        vB[nb * 4 + r] = sB[nb][r];
      }
    if (kt == qtB) {
      int qg = wave * 16 + l15;
#pragma unroll
      for (int i = 0; i < 16; ++i) {
        int kg = (i >> 2) * 16 + l4 * 4 + (i & 3);
        if (kg > qg) vB[i] = -1e30f;
      }
    }
    // interleaved tree max (depth 4)
    float tA[8], tB[8];
#pragma unroll
    for (int i = 0; i < 8; ++i) {
      tA[i] = fmaxf(vA[2 * i], vA[2 * i + 1]);
      tB[i] = fmaxf(vB[2 * i], vB[2 * i + 1]);
    }
#pragma unroll
    for (int i = 0; i < 4; ++i) {
      tA[i] = fmaxf(tA[i], tA[i + 4]);
      tB[i] = fmaxf(tB[i], tB[i + 4]);
    }
    float mxA = fmaxf(fmaxf(tA[0], tA[2]), fmaxf(tA[1], tA[3]));
    float mxB = fmaxf(fmaxf(tB[0], tB[2]), fmaxf(tB[1], tB[3]));
    // combined defer-max (rescale both on the rare growth tile; alpha<=1 safe)
    if (!__all(fmaxf(mxA - mA, mxB - mB) <= 8.0f)) {
      float mrA = fmaxf(mxA, __shfl_xor(mxA, 16));
      float mrB = fmaxf(mxB, __shfl_xor(mxB, 16));
      mrA = fmaxf(mrA, __shfl_xor(mrA, 32));
      mrB = fmaxf(mrB, __shfl_xor(mrB, 32));
      float mnA = fmaxf(mA, mrA), mnB = fmaxf(mB, mrB);
      float aA = ex2(mA - mnA), aB = ex2(mB - mnB);
      mA = mnA;
      mB = mnB;
      lsA *= aA;
      lsB *= aB;
#pragma unroll
      for (int hb = 0; hb < 4; ++hb)
#pragma unroll
        for (int r = 0; r < 4; ++r) {
          oA[hb][r] *= aA;
          oB[hb][r] *= aB;
        }
    }
    float pA[16], pB[16];
#pragma unroll
    for (int i = 0; i < 16; ++i) {
      pA[i] = ex2(vA[i] - mA);
      pB[i] = ex2(vB[i] - mB);
    }
    // interleaved tree sum
    float uA[8], uB[8];
#pragma unroll
    for (int i = 0; i < 8; ++i) {
      uA[i] = pA[2 * i] + pA[2 * i + 1];
      uB[i] = pB[2 * i] + pB[2 * i + 1];
    }
#pragma unroll
    for (int i = 0; i < 4; ++i) {
      uA[i] += uA[i + 4];
      uB[i] += uB[i + 4];
    }
    lsA += (uA[0] + uA[2]) + (uA[1] + uA[3]);
    lsB += (uB[0] + uB[2]) + (uB[1] + uB[3]);
    // pack P
    bf16x8 pfA[2], pfB[2];
#pragma unroll
    for (int s = 0; s < 2; ++s) {
      u32x4 wa, wb;
      wa.x = cvt_pk_bf16(pA[8 * s + 0], pA[8 * s + 1]);
      wb.x = cvt_pk_bf16(pB[8 * s + 0], pB[8 * s + 1]);
      wa.y = cvt_pk_bf16(pA[8 * s + 2], pA[8 * s + 3]);
      wb.y = cvt_pk_bf16(pB[8 * s + 2], pB[8 * s + 3]);
      wa.z = cvt_pk_bf16(pA[8 * s + 4], pA[8 * s + 5]);
      wb.z = cvt_pk_bf16(pB[8 * s + 4], pB[8 * s + 5]);
      wa.w = cvt_pk_bf16(pA[8 * s + 6], pA[8 * s + 7]);
      wb.w = cvt_pk_bf16(pB[8 * s + 6], pB[8 * s + 7]);
      pfA[s] = __builtin_bit_cast(bf16x8, wa);
      pfB[s] = __builtin_bit_cast(bf16x8, wb);
    }
    // SHARED vf tr-reads (16, was 32)
    bf16x8 vf[2][4];
#pragma unroll
    for (int s = 0; s < 2; ++s)
#pragma unroll
      for (int hb = 0; hb < 4; ++hb) {
        bf16x4 ta = tr16(&Vtr[cur][(hb * 16 + s * 8) * 64 + lane * 4]);
        bf16x4 tb = tr16(&Vtr[cur][(hb * 16 + s * 8 + 4) * 64 + lane * 4]);
        vf[s][hb] = __builtin_shufflevector(ta, tb, 0, 1, 2, 3, 4, 5, 6, 7);
      }
    asm volatile("s_waitcnt lgkmcnt(0)" ::: "memory");
    __builtin_amdgcn_sched_barrier(0);
    __builtin_amdgcn_s_setprio(1);
#pragma unroll
    for (int s = 0; s < 2; ++s)
#pragma unroll
      for (int hb = 0; hb < 4; ++hb) {
        oA[hb] = __builtin_amdgcn_mfma_f32_16x16x32_bf16(vf[s][hb], pfA[s], oA[hb], 0, 0, 0);
        oB[hb] = __builtin_amdgcn_mfma_f32_16x16x32_bf16(vf[s][hb], pfB[s], oB[hb], 0, 0, 0);
      }
    __builtin_amdgcn_s_setprio(0);

    __builtin_amdgcn_s_barrier();
    __builtin_amdgcn_sched_barrier(0);
    int nt = kt + 3 > qtA ? qtA : kt + 3;
    stage(cur, nt);
    cur = cur == 2 ? 0 : cur + 1;
  }

  // ======== phase 2: A only (kt = qtB+1..qtA) ========
#pragma unroll 1
  for (; kt <= qtA; ++kt) {
    asm volatile("s_waitcnt vmcnt(8)" ::: "memory");
    __builtin_amdgcn_s_barrier();
    __builtin_amdgcn_sched_barrier(0);

    f32x4 sA[4] = {fz, fz, fz, fz};
    __builtin_amdgcn_s_setprio(1);
#pragma unroll
    for (int s = 0; s < 2; ++s)
#pragma unroll
      for (int nb = 0; nb < 4; ++nb) {
        int kk = nb * 16 + l15;
        int ch = (s * 4 + l4) ^ (kk & 7);
        bf16x8 kf = *(const bf16x8*)&Kl[cur][kk * 64 + ch * 8];
        sA[nb] = __builtin_amdgcn_mfma_f32_16x16x32_bf16(kf, qfA[s], sA[nb], 0, 0, 0);
      }
    __builtin_amdgcn_s_setprio(0);

    float vA[16];
#pragma unroll
    for (int nb = 0; nb < 4; ++nb)
#pragma unroll
      for (int r = 0; r < 4; ++r) vA[nb * 4 + r] = sA[nb][r];
    if (kt == qtA) {
      int qg = wave * 16 + l15;
#pragma unroll
      for (int i = 0; i < 16; ++i) {
        int kg = (i >> 2) * 16 + l4 * 4 + (i & 3);
        if (kg > qg) vA[i] = -1e30f;
      }
    }
    float tA[8];
#pragma unroll
    for (int i = 0; i < 8; ++i) tA[i] = fmaxf(vA[2 * i], vA[2 * i + 1]);
#pragma unroll
    for (int i = 0; i < 4; ++i) tA[i] = fmaxf(tA[i], tA[i + 4]);
    float mxA = fmaxf(fmaxf(tA[0], tA[2]), fmaxf(tA[1], tA[3]));
    if (!__all(mxA <= mA + 8.0f)) {
      float mrA = fmaxf(mxA, __shfl_xor(mxA, 16));
      mrA = fmaxf(mrA, __shfl_xor(mrA, 32));
      float mnA = fmaxf(mA, mrA);
      float aA = ex2(mA - mnA);
      mA = mnA;
      lsA *= aA;
#pragma unroll
      for (int hb = 0; hb < 4; ++hb)
#pragma unroll
        for (int r = 0; r < 4; ++r) oA[hb][r] *= aA;
    }
    float pA[16];
#pragma unroll
    for (int i = 0; i < 16; ++i) pA[i] = ex2(vA[i] - mA);
    float uA[8];
#pragma unroll
    for (int i = 0; i < 8; ++i) uA[i] = pA[2 * i] + pA[2 * i + 1];
#pragma unroll
    for (int i = 0; i < 4; ++i) uA[i] += uA[i + 4];
    lsA += (uA[0] + uA[2]) + (uA[1] + uA[3]);
    bf16x8 pfA[2];
#pragma unroll
    for (int s = 0; s < 2; ++s) {
      u32x4 wa;
      wa.x = cvt_pk_bf16(pA[8 * s + 0], pA[8 * s + 1]);
      wa.y = cvt_pk_bf16(pA[8 * s + 2], pA[8 * s + 3]);
      wa.z = cvt_pk_bf16(pA[8 * s + 4], pA[8 * s + 5]);
      wa.w = cvt_pk_bf16(pA[8 * s + 6], pA[8 * s + 7]);
      pfA[s] = __builtin_bit_cast(bf16x8, wa);
    }
    bf16x8 vf[2][4];
#pragma unroll
    for (int s = 0; s < 2; ++s)
#pragma unroll
      for (int hb = 0; hb < 4; ++hb) {
        bf16x4 ta = tr16(&Vtr[cur][(hb * 16 + s * 8) * 64 + lane * 4]);
        bf16x4 tb = tr16(&Vtr[cur][(hb * 16 + s * 8 + 4) * 64 + lane * 4]);
        vf[s][hb] = __builtin_shufflevector(ta, tb, 0, 1, 2, 3, 4, 5, 6, 7);
      }
    asm volatile("s_waitcnt lgkmcnt(0)" ::: "memory");
    __builtin_amdgcn_sched_barrier(0);
    __builtin_amdgcn_s_setprio(1);
#pragma unroll
    for (int s = 0; s < 2; ++s)
#pragma unroll
      for (int hb = 0; hb < 4; ++hb)
        oA[hb] = __builtin_amdgcn_mfma_f32_16x16x32_bf16(vf[s][hb], pfA[s], oA[hb], 0, 0, 0);
    __builtin_amdgcn_s_setprio(0);

    __builtin_amdgcn_s_barrier();
    __builtin_amdgcn_sched_barrier(0);
    int nt = kt + 3 > qtA ? qtA : kt + 3;
    stage(cur, nt);
    cur = cur == 2 ? 0 : cur + 1;
  }

  // epilogue: merge group-partial lsum (2 shuffles), divide, store
  auto epi = [&](f32x4* accO, float lsum, int qt) {
    float t = lsum + __shfl_xor(lsum, 16);
    t += __shfl_xor(t, 32);
    float inv = 1.0f / t;
    int qg = qt * 64 + wave * 16 + l15;
    u16* yrow = Y + (size_t)(b * 2048 + qg) * 1024 + h * 64;
#pragma unroll
    for (int hb = 0; hb < 4; ++hb) {
      uint2 pk;
      pk.x = cvt_pk_bf16(accO[hb][0] * inv, accO[hb][1] * inv);
      pk.y = cvt_pk_bf16(accO[hb][2] * inv, accO[hb][3] * inv);
      *(uint2*)&yrow[hb * 16 + l4 * 4] = pk;
    }
  };
  epi(oA, lsA, qtA);
  epi(oB, lsB, qtB);
}

extern "C" void kernel_launch(void* const* d_in, const int* in_sizes, int n_in,
                              void* d_out, int out_size, void* d_ws, size_t ws_size,
                              hipStream_t stream) {
  const float* x = (const float*)d_in[0];       // [2,2048,1024]
  const float* Wqkv = (const float*)d_in[1];    // [1024,3072]
  const float* Wproj = (const float*)d_in[2];   // [1024,1024]
  float* out = (float*)d_out;                   // [2,2048,1024] f32

  char* ws = (char*)d_ws;
  u16* Xb  = (u16*)(ws + 0);                    // 8 MB  [4096][1024]
  u16* Wqt = (u16*)(ws + ((size_t)8 << 20));    // 6 MB  [3072][1024]
  u16* Wpt = (u16*)(ws + ((size_t)14 << 20));   // 2 MB  [1024][1024]
  u16* Qs  = (u16*)(ws + ((size_t)16 << 20));   // 8 MB  [2,16,2048,64]
  u16* Ks  = (u16*)(ws + ((size_t)24 << 20));   // 8 MB
  u16* Vs  = (u16*)(ws + ((size_t)32 << 20));   // 8 MB
  u16* Yb  = (u16*)(ws + ((size_t)40 << 20));   // 8 MB  [4096][1024]

  k_cast<<<2048, 256, 0, stream>>>(x, Xb, 4096 * 1024 / 8);
  k_tcast<<<dim3(96, 32), 256, 0, stream>>>(Wqkv, Wqt, 1024, 3072);
  k_tcast<<<dim3(32, 32), 256, 0, stream>>>(Wproj, Wpt, 1024, 1024);
  k_gemm<0><<<dim3(24, 32), 256, 0, stream>>>(Xb, Wqt, Qs, Ks, Vs, nullptr, 1024);
  k_attn<<<dim3(16, 32), 256, 0, stream>>>(Qs, Ks, Vs, Yb);
  k_gemm<1><<<dim3(8, 32), 256, 0, stream>>>(Yb, Wpt, nullptr, nullptr, nullptr, out, 1024);
}